// Round 9
// baseline (16.226 us; speedup 1.0000x reference)
//
#include <hip/hip_runtime.h>
#include <hip/hip_bf16.h>

constexpr int Bn = 4096;
constexpr int Dn = 128;
constexpr int Cn = 256;
constexpr int Wr = Cn + Dn;   // 384 rows of W = [G'^T (256) | alpha (128)]

typedef __attribute__((ext_vector_type(8))) short bf16x8;  // 8 bf16 = 4 VGPR
typedef __attribute__((ext_vector_type(4))) float f32x4;

static __device__ inline unsigned short f2bfu(float f) {
    __hip_bfloat16 h = __float2bfloat16(f);
    return *reinterpret_cast<unsigned short*>(&h);
}
static __device__ inline float bfu2f(unsigned short u) {
    __hip_bfloat16 h = *reinterpret_cast<__hip_bfloat16*>(&u);
    return __bfloat162float(h);
}
static __device__ inline unsigned pk2(float x, float y) {
    return (unsigned)f2bfu(x) | ((unsigned)f2bfu(y) << 16);
}

// XOR-swizzled byte offset for 256B-row bf16 LDS tiles (bank-conflict fix):
#define SWZ_OFF(row, e) ((row) * 256 + ((((e) * 2)) ^ (((row) & 7) << 4)))

// ---------------- setup: W[384][128] bf16 + tvec[256] fp32 ----------------
// blocks 0-7:  G'-part for c in [32b, 32b+32): W[c][d] = bf16(G'[d][c]), tvec[c]
// blocks 8-15: alpha passthrough rows [16(b-8), +16): W[256+d][e] = bf16(a[d][e])
__global__ __launch_bounds__(512) void setup_kernel(
    const float* __restrict__ means, const float* __restrict__ alpha,
    unsigned short* __restrict__ W, float* __restrict__ tvec) {
    const int tid = threadIdx.x;

    if ((int)blockIdx.x >= 8) {
        const int r0 = ((int)blockIdx.x - 8) * 16;     // 16 alpha rows
        const int d = tid >> 5;                         // 32 float4 per row
        const int e0 = (tid & 31) << 2;
        float4 v = *(const float4*)&alpha[(r0 + d) * Dn + e0];
        unsigned* p = (unsigned*)&W[(Cn + r0 + d) * Dn + e0];
        p[0] = pk2(v.x, v.y);
        p[1] = pk2(v.z, v.w);
        return;
    }

    __shared__ __align__(16) unsigned char AL[Dn * 256];   // bf16 alpha, swizzled
    __shared__ __align__(16) unsigned char MTl[32 * 256];  // bf16 means^T, 32 local cols
    __shared__ float TP[2][16][4];
    const int cbase = (int)blockIdx.x * 32;
    const int lane = tid & 63;
    const int l15 = lane & 15;
    const int lh = lane >> 4;
    const int w = tid >> 6;

    // stage alpha -> AL (full 128x128)
    {
        const float4* a4 = (const float4*)alpha;
        #pragma unroll
        for (int i = 0; i < 8; ++i) {
            int idx4 = tid + i * 512;
            int d = idx4 >> 5, e0 = (idx4 & 31) << 2;
            float4 v = a4[idx4];
            unsigned char* p = AL + SWZ_OFF(d, e0);
            *(unsigned*)p = pk2(v.x, v.y);
            *(unsigned*)(p + 4) = pk2(v.z, v.w);
        }
    }
    // stage means^T for local cols (4x4 register transpose), threads 0-255
    if (tid < 256) {
        const int cbl = tid & 7;      // local c-block: c = 4cbl..4cbl+3
        const int db = tid >> 3;      // 0..31: d = 4db..4db+3
        float4 v0 = *(const float4*)&means[(4 * db + 0) * Cn + cbase + 4 * cbl];
        float4 v1 = *(const float4*)&means[(4 * db + 1) * Cn + cbase + 4 * cbl];
        float4 v2 = *(const float4*)&means[(4 * db + 2) * Cn + cbase + 4 * cbl];
        float4 v3 = *(const float4*)&means[(4 * db + 3) * Cn + cbase + 4 * cbl];
        uint2 pk;
        pk.x = pk2(v0.x, v1.x); pk.y = pk2(v2.x, v3.x);
        *(uint2*)(MTl + SWZ_OFF(4 * cbl + 0, 4 * db)) = pk;
        pk.x = pk2(v0.y, v1.y); pk.y = pk2(v2.y, v3.y);
        *(uint2*)(MTl + SWZ_OFF(4 * cbl + 1, 4 * db)) = pk;
        pk.x = pk2(v0.z, v1.z); pk.y = pk2(v2.z, v3.z);
        *(uint2*)(MTl + SWZ_OFF(4 * cbl + 2, 4 * db)) = pk;
        pk.x = pk2(v0.w, v1.w); pk.y = pk2(v2.w, v3.w);
        *(uint2*)(MTl + SWZ_OFF(4 * cbl + 3, 4 * db)) = pk;
    }
    __syncthreads();

    // G'-GEMM: wave w -> col-tile ct = w&1, row-tiles mt in {2q, 2q+1}, q = w>>1
    const int ct = w & 1, q = w >> 1;
    f32x4 acc[2];
    acc[0] = (f32x4){0.f, 0.f, 0.f, 0.f};
    acc[1] = (f32x4){0.f, 0.f, 0.f, 0.f};
    #pragma unroll
    for (int k0 = 0; k0 < 4; ++k0) {
        bf16x8 b = *(const bf16x8*)(MTl + SWZ_OFF(16 * ct + l15, 32 * k0 + 8 * lh));
        #pragma unroll
        for (int s = 0; s < 2; ++s) {
            bf16x8 a = *(const bf16x8*)(AL + SWZ_OFF(16 * (2 * q + s) + l15, 32 * k0 + 8 * lh));
            acc[s] = __builtin_amdgcn_mfma_f32_16x16x32_bf16(a, b, acc[s], 0, 0, 0);
        }
    }
    // W writes (c-major rows) + t partial. C layout: col=l15, row=4lh+reg.
    const int c = cbase + 16 * ct + l15;
    float tpart = 0.f;
    #pragma unroll
    for (int s = 0; s < 2; ++s) {
        const int mt = 2 * q + s;
        uint2 mm = *(const uint2*)(MTl + SWZ_OFF(16 * ct + l15, 16 * mt + 4 * lh));
        tpart = fmaf(bfu2f((unsigned short)(mm.x & 0xffffu)), acc[s][0], tpart);
        tpart = fmaf(bfu2f((unsigned short)(mm.x >> 16)),     acc[s][1], tpart);
        tpart = fmaf(bfu2f((unsigned short)(mm.y & 0xffffu)), acc[s][2], tpart);
        tpart = fmaf(bfu2f((unsigned short)(mm.y >> 16)),     acc[s][3], tpart);
        uint2 pk;
        pk.x = pk2(acc[s][0], acc[s][1]);
        pk.y = pk2(acc[s][2], acc[s][3]);
        *(uint2*)&W[c * Dn + 16 * mt + 4 * lh] = pk;   // 8B aligned
    }
    tpart += __shfl_xor(tpart, 16);   // reduce over lh
    tpart += __shfl_xor(tpart, 32);
    if (lane < 16) TP[ct][l15][q] = tpart;
    __syncthreads();
    if (tid < 32)
        tvec[cbase + tid] = TP[tid >> 4][tid & 15][0] + TP[tid >> 4][tid & 15][1] +
                            TP[tid >> 4][tid & 15][2] + TP[tid >> 4][tid & 15][3];
}

// ---------------- main: out[b] = x^T a x + min_c( t[c] - 2 x.G'[:,c] ) ----------------
// 256 blocks x 512 thr (8 waves), block = 16 X-rows. B-frags straight from global W.
// Wave w: tiles tg = 3w..3w+2 of 24; W row = 16*tg + l15 (tg<16: S-col c; tg>=16: alpha row d).
__global__ __launch_bounds__(512) void main_kernel(
    const float* __restrict__ X, const unsigned short* __restrict__ W,
    const float* __restrict__ tvec, float* __restrict__ out) {
    __shared__ __align__(16) unsigned char XL[16 * 256];  // bf16 X-tile, swizzled
    __shared__ float SMIN[8][16];
    __shared__ float SXAX[8][16];

    const int tid = threadIdx.x;
    const int w = tid >> 6;
    const int lane = tid & 63;
    const int l15 = lane & 15;
    const int lh = lane >> 4;
    const int b0 = blockIdx.x * 16;

    // stage X-tile (2048 floats, 1 float4/thread)
    {
        float4 v = ((const float4*)(X + b0 * Dn))[tid];
        const int b = tid >> 5;
        const int e0 = (tid & 31) << 2;
        uint2 pk;
        pk.x = pk2(v.x, v.y); pk.y = pk2(v.z, v.w);
        *(uint2*)(XL + SWZ_OFF(b, e0)) = pk;
    }

    // B-frags from global W (L2/L3-resident bf16) + t gather — issue before barrier
    bf16x8 bfr[3][4];
    float tcv[3];
    #pragma unroll
    for (int j2 = 0; j2 < 3; ++j2) {
        const int tg = 3 * w + j2;
        const unsigned short* wrow = W + (16 * tg + l15) * Dn;
        #pragma unroll
        for (int k0 = 0; k0 < 4; ++k0)
            bfr[j2][k0] = *(const bf16x8*)(wrow + 32 * k0 + 8 * lh);
        tcv[j2] = (tg < 16) ? tvec[16 * tg + l15] : 0.f;
    }
    __syncthreads();

    bf16x8 af[4];
    #pragma unroll
    for (int k0 = 0; k0 < 4; ++k0)
        af[k0] = *(const bf16x8*)(XL + SWZ_OFF(l15, 32 * k0 + 8 * lh));

    f32x4 macc[3];
    #pragma unroll
    for (int j2 = 0; j2 < 3; ++j2) macc[j2] = (f32x4){0.f, 0.f, 0.f, 0.f};
    #pragma unroll
    for (int k0 = 0; k0 < 4; ++k0)
        #pragma unroll
        for (int j2 = 0; j2 < 3; ++j2)
            macc[j2] = __builtin_amdgcn_mfma_f32_16x16x32_bf16(af[k0], bfr[j2][k0], macc[j2], 0, 0, 0);

    // epilogue: C layout col=l15 (W-row in tile), row=4lh+reg (=b)
    {
        float mr[4], px[4];
        #pragma unroll
        for (int r = 0; r < 4; ++r) { mr[r] = 1e30f; px[r] = 0.f; }
        #pragma unroll
        for (int j2 = 0; j2 < 3; ++j2) {
            const int tg = 3 * w + j2;
            if (tg < 16) {
                #pragma unroll
                for (int r = 0; r < 4; ++r)
                    mr[r] = fminf(mr[r], tcv[j2] - 2.f * macc[j2][r]);   // -2 x^T (a m_c)
            } else {
                const int d = 16 * (tg - 16) + l15;
                #pragma unroll
                for (int r = 0; r < 4; ++r) {
                    unsigned short u = *(const unsigned short*)(XL + SWZ_OFF(4 * lh + r, d));
                    px[r] = fmaf(macc[j2][r], bfu2f(u), px[r]);
                }
            }
        }
        #pragma unroll
        for (int r = 0; r < 4; ++r) {
            #pragma unroll
            for (int m = 1; m < 16; m <<= 1) {
                mr[r] = fminf(mr[r], __shfl_xor(mr[r], m));
                px[r] += __shfl_xor(px[r], m);
            }
        }
        if (l15 == 0) {
            #pragma unroll
            for (int r = 0; r < 4; ++r) {
                SMIN[w][4 * lh + r] = mr[r];
                SXAX[w][4 * lh + r] = px[r];
            }
        }
    }
    __syncthreads();

    if (tid < 16) {
        float mnv = 1e30f, xa = 0.f;
        #pragma unroll
        for (int w8 = 0; w8 < 8; ++w8) {
            mnv = fminf(mnv, SMIN[w8][tid]);
            xa += SXAX[w8][tid];
        }
        out[b0 + tid] = xa + mnv;   // xa = x^T a x
    }
}

extern "C" void kernel_launch(void* const* d_in, const int* in_sizes, int n_in,
                              void* d_out, int out_size, void* d_ws, size_t ws_size,
                              hipStream_t stream) {
    const float* X     = (const float*)d_in[0];
    const float* means = (const float*)d_in[1];
    const float* alpha = (const float*)d_in[2];
    float* out = (float*)d_out;
    unsigned short* W = (unsigned short*)d_ws;                  // [384*128] bf16
    float* tvec = (float*)((char*)d_ws + Wr * Dn * sizeof(unsigned short));  // [256] fp32

    setup_kernel<<<16, 512, 0, stream>>>(means, alpha, W, tvec);
    main_kernel<<<Bn / 16, 512, 0, stream>>>(X, W, tvec, out);
}

// Round 10
// 11.513 us; speedup vs baseline: 1.4094x; 1.4094x over previous
//
#include <hip/hip_runtime.h>
#include <hip/hip_bf16.h>

constexpr int Bn = 4096;
constexpr int Dn = 128;
constexpr int Cn = 256;

typedef __attribute__((ext_vector_type(8))) short bf16x8;  // 8 bf16 = 4 VGPR
typedef __attribute__((ext_vector_type(4))) float f32x4;

static __device__ inline unsigned short f2bfu(float f) {
    __hip_bfloat16 h = __float2bfloat16(f);
    return *reinterpret_cast<unsigned short*>(&h);
}
static __device__ inline float bfu2f(unsigned short u) {
    __hip_bfloat16 h = *reinterpret_cast<__hip_bfloat16*>(&u);
    return __bfloat162float(h);
}
static __device__ inline unsigned pk2(float x, float y) {
    return (unsigned)f2bfu(x) | ((unsigned)f2bfu(y) << 16);
}

// XOR-swizzled byte offset for 256B-row bf16 tiles (rows of 128 bf16):
#define SWZ_OFF(row, e) ((row) * 256 + ((((e) * 2)) ^ (((row) & 7) << 4)))

// Single fused kernel: 256 blocks x 512 threads (8 waves), block = 16 rows of X.
//   q[b,c] = x^T a x - 2 x^T (a m_c) + m_c^T (a m_c)
// Phase C: G' = a*means, wave = 4 col-tiles (cg=w&3) x 4 row-tiles (rg=w>>2)
//          + H-tile (a*X^T, rows 16w..16w+15) with B = af (XL row, reused in F)
// Phase D: partial t[c] over this wave's d-half -> TP[rg][c]  (fp32)
// [barrier: other waves still read means from MT in C/D]
// Phase E: overwrite MT with bf16 G' (wave's own (c, d-half) slots)
// [barrier]
// Phase F: S' = X*G' (2 tiles/wave, af reused), min epilogue t = TP[0]+TP[1].
__global__ __launch_bounds__(512) void fused_kernel(
    const float* __restrict__ X, const float* __restrict__ means,
    const float* __restrict__ alpha, float* __restrict__ out) {
    __shared__ __align__(16) unsigned char AL[Dn * 256];  // 32768B: bf16 alpha, swizzled
    __shared__ __align__(16) unsigned char MT[Cn * 256];  // 65536B: bf16 means^T; later G'
    __shared__ __align__(16) unsigned char XL[16 * 256];  // 4096B:  bf16 X-tile, swizzled
    __shared__ float TP[2][Cn];                            // 2KB: t partials per d-half
    __shared__ float SMIN[8][16];
    __shared__ float SXAX[8][16];

    const int tid = threadIdx.x;
    const int w = tid >> 6;          // wave 0..7
    const int lane = tid & 63;
    const int l15 = lane & 15;
    const int lh = lane >> 4;        // 0..3
    const int b0 = blockIdx.x * 16;
    const int cg = w & 3;            // col-group: cols 64cg..64cg+63
    const int rg = w >> 2;           // row-group: d in [64rg, 64rg+64)

    // ---------- Phase A: stage X-tile, alpha, means^T (all bf16, swizzled) ----------
    {
        {
            float4 v = ((const float4*)(X + b0 * Dn))[tid];
            const int b = tid >> 5;
            const int e0 = (tid & 31) << 2;
            uint2 pk;
            pk.x = pk2(v.x, v.y); pk.y = pk2(v.z, v.w);
            *(uint2*)(XL + SWZ_OFF(b, e0)) = pk;
        }
        const float4* a4 = (const float4*)alpha;
        #pragma unroll
        for (int i = 0; i < 8; ++i) {
            int idx4 = tid + i * 512;
            int d = idx4 >> 5, e0 = (idx4 & 31) << 2;
            float4 v = a4[idx4];
            unsigned char* p = AL + SWZ_OFF(d, e0);
            *(unsigned*)p = pk2(v.x, v.y);
            *(unsigned*)(p + 4) = pk2(v.z, v.w);
        }
        // means^T: wave w stages c in [32w, 32w+32) via 4x4 register transpose
        const int cb = 8 * w + (lane & 7);       // c = 4cb..4cb+3
        const int db0 = lane >> 3;               // 0..7
        #pragma unroll
        for (int i = 0; i < 4; ++i) {
            const int db = db0 + 8 * i;          // d = 4db..4db+3
            float4 v0 = *(const float4*)&means[(4 * db + 0) * Cn + 4 * cb];
            float4 v1 = *(const float4*)&means[(4 * db + 1) * Cn + 4 * cb];
            float4 v2 = *(const float4*)&means[(4 * db + 2) * Cn + 4 * cb];
            float4 v3 = *(const float4*)&means[(4 * db + 3) * Cn + 4 * cb];
            uint2 pk;
            pk.x = pk2(v0.x, v1.x); pk.y = pk2(v2.x, v3.x);
            *(uint2*)(MT + SWZ_OFF(4 * cb + 0, 4 * db)) = pk;
            pk.x = pk2(v0.y, v1.y); pk.y = pk2(v2.y, v3.y);
            *(uint2*)(MT + SWZ_OFF(4 * cb + 1, 4 * db)) = pk;
            pk.x = pk2(v0.z, v1.z); pk.y = pk2(v2.z, v3.z);
            *(uint2*)(MT + SWZ_OFF(4 * cb + 2, 4 * db)) = pk;
            pk.x = pk2(v0.w, v1.w); pk.y = pk2(v2.w, v3.w);
            *(uint2*)(MT + SWZ_OFF(4 * cb + 3, 4 * db)) = pk;
        }
    }
    __syncthreads();

    // ---------- Phase C: G' GEMM (4col x 4row) + H-tile + af hoist ----------
    f32x4 gacc[4][4];                 // [col-tile j][row-tile s: mt = 4rg+s]
    #pragma unroll
    for (int j = 0; j < 4; ++j)
        #pragma unroll
        for (int s = 0; s < 4; ++s) gacc[j][s] = (f32x4){0.f, 0.f, 0.f, 0.f};
    f32x4 xacc = (f32x4){0.f, 0.f, 0.f, 0.f};
    bf16x8 af[4];                     // XL row l15 — B for H-tile AND A for Phase F

    #pragma unroll
    for (int k0 = 0; k0 < 4; ++k0) {
        af[k0] = *(const bf16x8*)(XL + SWZ_OFF(l15, 32 * k0 + 8 * lh));
        bf16x8 bj[4];
        #pragma unroll
        for (int j = 0; j < 4; ++j) {
            const int c = 64 * cg + 16 * j + l15;
            bj[j] = *(const bf16x8*)(MT + SWZ_OFF(c, 32 * k0 + 8 * lh));
        }
        #pragma unroll
        for (int s = 0; s < 4; ++s) {
            const int mt = 4 * rg + s;
            bf16x8 a = *(const bf16x8*)(AL + SWZ_OFF(16 * mt + l15, 32 * k0 + 8 * lh));
            #pragma unroll
            for (int j = 0; j < 4; ++j)
                gacc[j][s] = __builtin_amdgcn_mfma_f32_16x16x32_bf16(a, bj[j], gacc[j][s], 0, 0, 0);
        }
        // H-tile rows 16w..16w+15: C[d][b] = sum_e a[d][e] X[b][e]; B = af (X rows)
        {
            bf16x8 aH = *(const bf16x8*)(AL + SWZ_OFF(16 * w + l15, 32 * k0 + 8 * lh));
            xacc = __builtin_amdgcn_mfma_f32_16x16x32_bf16(aH, af[k0], xacc, 0, 0, 0);
        }
    }

    // xax partial: lane (b=l15, lh) holds H[16w+4lh+r][b]; dot with x[b][same d]
    {
        uint2 pk = *(const uint2*)(XL + SWZ_OFF(l15, 16 * w + 4 * lh));
        float v = bfu2f((unsigned short)(pk.x & 0xffffu)) * xacc[0];
        v = fmaf(bfu2f((unsigned short)(pk.x >> 16)),     xacc[1], v);
        v = fmaf(bfu2f((unsigned short)(pk.y & 0xffffu)), xacc[2], v);
        v = fmaf(bfu2f((unsigned short)(pk.y >> 16)),     xacc[3], v);
        v += __shfl_xor(v, 16);
        v += __shfl_xor(v, 32);
        if (lane < 16) SXAX[w][lane] = v;
    }

    // ---------- Phase D: partial t[c] over this wave's d-half ----------
    {
        float tpart[4];
        #pragma unroll
        for (int j = 0; j < 4; ++j) {
            const int c = 64 * cg + 16 * j + l15;
            float v = 0.f;
            #pragma unroll
            for (int s = 0; s < 4; ++s) {
                const int mt = 4 * rg + s;
                uint2 mm = *(const uint2*)(MT + SWZ_OFF(c, 16 * mt + 4 * lh));
                v = fmaf(bfu2f((unsigned short)(mm.x & 0xffffu)), gacc[j][s][0], v);
                v = fmaf(bfu2f((unsigned short)(mm.x >> 16)),     gacc[j][s][1], v);
                v = fmaf(bfu2f((unsigned short)(mm.y & 0xffffu)), gacc[j][s][2], v);
                v = fmaf(bfu2f((unsigned short)(mm.y >> 16)),     gacc[j][s][3], v);
            }
            v += __shfl_xor(v, 16);   // reduce over lh (butterfly, all lanes get sum)
            v += __shfl_xor(v, 32);
            tpart[j] = v;
        }
        if (lane < 16)
            #pragma unroll
            for (int j = 0; j < 4; ++j) TP[rg][64 * cg + 16 * j + lane] = tpart[j];
    }
    __syncthreads();   // other waves' C/D means-reads (full d-range) before E writes

    // ---------- Phase E: overwrite MT with G' (this wave's (c, d-half) slots) ----------
    #pragma unroll
    for (int j = 0; j < 4; ++j) {
        const int c = 64 * cg + 16 * j + l15;
        #pragma unroll
        for (int s = 0; s < 4; ++s) {
            const int mt = 4 * rg + s;
            uint2 pk;
            pk.x = pk2(gacc[j][s][0], gacc[j][s][1]);
            pk.y = pk2(gacc[j][s][2], gacc[j][s][3]);
            *(uint2*)(MT + SWZ_OFF(c, 16 * mt + 4 * lh)) = pk;
        }
    }
    __syncthreads();

    // ---------- Phase F: S' = X*G' -- wave w: tiles 2w, 2w+1 of 16 (af reused) ----------
    bf16x8 bf2[2][4];
    #pragma unroll
    for (int j2 = 0; j2 < 2; ++j2) {
        const int rowc = 16 * (2 * w + j2) + l15;
        #pragma unroll
        for (int k0 = 0; k0 < 4; ++k0)
            bf2[j2][k0] = *(const bf16x8*)(MT + SWZ_OFF(rowc, 32 * k0 + 8 * lh));
    }
    f32x4 macc[2];
    #pragma unroll
    for (int j2 = 0; j2 < 2; ++j2) macc[j2] = (f32x4){0.f, 0.f, 0.f, 0.f};
    #pragma unroll
    for (int k0 = 0; k0 < 4; ++k0)
        #pragma unroll
        for (int j2 = 0; j2 < 2; ++j2)
            macc[j2] = __builtin_amdgcn_mfma_f32_16x16x32_bf16(af[k0], bf2[j2][k0], macc[j2], 0, 0, 0);

    // epilogue: C layout col=l15 (=c within tile), row=4lh+reg (=b)
    {
        float mr[4];
        #pragma unroll
        for (int r = 0; r < 4; ++r) mr[r] = 1e30f;
        #pragma unroll
        for (int j2 = 0; j2 < 2; ++j2) {
            const int c = 16 * (2 * w + j2) + l15;
            const float tc = TP[0][c] + TP[1][c];
            #pragma unroll
            for (int r = 0; r < 4; ++r)
                mr[r] = fminf(mr[r], tc - 2.f * macc[j2][r]);   // -2 x^T (a m_c)
        }
        #pragma unroll
        for (int r = 0; r < 4; ++r) {
            #pragma unroll
            for (int m = 1; m < 16; m <<= 1)
                mr[r] = fminf(mr[r], __shfl_xor(mr[r], m));
        }
        if (l15 == 0)
            #pragma unroll
            for (int r = 0; r < 4; ++r) SMIN[w][4 * lh + r] = mr[r];
    }
    __syncthreads();

    if (tid < 16) {
        float mnv = 1e30f, xa = 0.f;
        #pragma unroll
        for (int w8 = 0; w8 < 8; ++w8) {
            mnv = fminf(mnv, SMIN[w8][tid]);
            xa += SXAX[w8][tid];
        }
        out[b0 + tid] = xa + mnv;   // xa = x^T a x
    }
}

extern "C" void kernel_launch(void* const* d_in, const int* in_sizes, int n_in,
                              void* d_out, int out_size, void* d_ws, size_t ws_size,
                              hipStream_t stream) {
    const float* X     = (const float*)d_in[0];
    const float* means = (const float*)d_in[1];
    const float* alpha = (const float*)d_in[2];
    float* out = (float*)d_out;
    fused_kernel<<<Bn / 16, 512, 0, stream>>>(X, means, alpha, out);
}

// Round 11
// 11.499 us; speedup vs baseline: 1.4111x; 1.0012x over previous
//
#include <hip/hip_runtime.h>
#include <hip/hip_bf16.h>

constexpr int Bn = 4096;
constexpr int Dn = 128;
constexpr int Cn = 256;

typedef __attribute__((ext_vector_type(8))) short bf16x8;  // 8 bf16 = 4 VGPR
typedef __attribute__((ext_vector_type(4))) float f32x4;

static __device__ inline unsigned short f2bfu(float f) {
    __hip_bfloat16 h = __float2bfloat16(f);
    return *reinterpret_cast<unsigned short*>(&h);
}
static __device__ inline float bfu2f(unsigned short u) {
    __hip_bfloat16 h = *reinterpret_cast<__hip_bfloat16*>(&u);
    return __bfloat162float(h);
}
static __device__ inline unsigned pk2(float x, float y) {
    return (unsigned)f2bfu(x) | ((unsigned)f2bfu(y) << 16);
}

// Byte-XOR swizzle for 256B-row bf16 tiles — used by AL/XL (b128 fragment reads).
#define SWZ_OFF(row, e) ((row) * 256 + ((((e) * 2)) ^ (((row) & 7) << 4)))
// Chunk-XOR layout for MD (means^T / G'): 8B chunks (4 bf16), chunk q = d/4 stored
// at position q ^ (c&15). All 8B accesses at (c=..+l15, q=f(lh)) are conflict-free:
// bank-pair = (q ^ l15) & 15 -> uniform 4-per-pair across a wave.
#define MD_OFF(c, q) ((c) * 256 + ((((q) ^ ((c) & 15))) << 3))

static __device__ inline bf16x8 md_row8(const unsigned char* base, int c, int q0) {
    // 8 consecutive-d bf16 (chunks q0, q0+1) of row c
    uint2 lo = *(const uint2*)(base + MD_OFF(c, q0));
    uint2 hi = *(const uint2*)(base + MD_OFF(c, q0 + 1));
    uint4 u;
    u.x = lo.x; u.y = lo.y; u.z = hi.x; u.w = hi.y;
    return *(bf16x8*)&u;
}

// Single fused kernel: 256 blocks x 512 threads (8 waves), block = 16 rows of X.
//   q[b,c] = x^T a x - 2 x^T (a m_c) + m_c^T (a m_c)
// Phase C: G' = a*means (4col x 4row tiles/wave) + H-tile (a*X^T) with B = af
// Phase D: partial t[c] over wave's d-half -> TP[rg][c]  (fp32)
// Phase E: overwrite MD with bf16 G' (same chunk layout)
// Phase F: S' = X*G' (2 tiles/wave, af reused), min epilogue t = TP[0]+TP[1].
__global__ __launch_bounds__(512) void fused_kernel(
    const float* __restrict__ X, const float* __restrict__ means,
    const float* __restrict__ alpha, float* __restrict__ out) {
    __shared__ __align__(16) unsigned char AL[Dn * 256];  // 32KB: bf16 alpha, byte-swizzled
    __shared__ __align__(16) unsigned char MD[Cn * 256];  // 64KB: bf16 means^T; later G' (chunk-XOR)
    __shared__ __align__(16) unsigned char XL[16 * 256];  // 4KB:  bf16 X-tile, byte-swizzled
    __shared__ float TP[2][Cn];                            // 2KB: t partials per d-half
    __shared__ float SMIN[8][16];
    __shared__ float SXAX[8][16];

    const int tid = threadIdx.x;
    const int w = tid >> 6;          // wave 0..7
    const int lane = tid & 63;
    const int l15 = lane & 15;
    const int lh = lane >> 4;        // 0..3
    const int b0 = blockIdx.x * 16;
    const int cg = w & 3;            // col-group: cols 64cg..64cg+63
    const int rg = w >> 2;           // row-group: d in [64rg, 64rg+64)

    // ---------- Phase A: stage X-tile, alpha (byte-swz), means^T (chunk-XOR) ----------
    {
        {
            float4 v = ((const float4*)(X + b0 * Dn))[tid];
            const int b = tid >> 5;
            const int e0 = (tid & 31) << 2;
            uint2 pk;
            pk.x = pk2(v.x, v.y); pk.y = pk2(v.z, v.w);
            *(uint2*)(XL + SWZ_OFF(b, e0)) = pk;
        }
        const float4* a4 = (const float4*)alpha;
        #pragma unroll
        for (int i = 0; i < 8; ++i) {
            int idx4 = tid + i * 512;
            int d = idx4 >> 5, e0 = (idx4 & 31) << 2;
            float4 v = a4[idx4];
            unsigned char* p = AL + SWZ_OFF(d, e0);
            *(unsigned*)p = pk2(v.x, v.y);
            *(unsigned*)(p + 4) = pk2(v.z, v.w);
        }
        // means^T via 4x4 register transpose into chunk-XOR MD
        const int cb = 8 * w + (lane & 7);       // c = 4cb..4cb+3
        const int db0 = lane >> 3;               // 0..7
        #pragma unroll
        for (int i = 0; i < 4; ++i) {
            const int db = db0 + 8 * i;          // chunk q = db; d = 4db..4db+3
            float4 v0 = *(const float4*)&means[(4 * db + 0) * Cn + 4 * cb];
            float4 v1 = *(const float4*)&means[(4 * db + 1) * Cn + 4 * cb];
            float4 v2 = *(const float4*)&means[(4 * db + 2) * Cn + 4 * cb];
            float4 v3 = *(const float4*)&means[(4 * db + 3) * Cn + 4 * cb];
            uint2 pk;
            pk.x = pk2(v0.x, v1.x); pk.y = pk2(v2.x, v3.x);
            *(uint2*)(MD + MD_OFF(4 * cb + 0, db)) = pk;
            pk.x = pk2(v0.y, v1.y); pk.y = pk2(v2.y, v3.y);
            *(uint2*)(MD + MD_OFF(4 * cb + 1, db)) = pk;
            pk.x = pk2(v0.z, v1.z); pk.y = pk2(v2.z, v3.z);
            *(uint2*)(MD + MD_OFF(4 * cb + 2, db)) = pk;
            pk.x = pk2(v0.w, v1.w); pk.y = pk2(v2.w, v3.w);
            *(uint2*)(MD + MD_OFF(4 * cb + 3, db)) = pk;
        }
    }
    __syncthreads();

    // ---------- Phase C: G' GEMM (4col x 4row) + H-tile + af hoist ----------
    f32x4 gacc[4][4];                 // [col-tile j][row-tile s: mt = 4rg+s]
    #pragma unroll
    for (int j = 0; j < 4; ++j)
        #pragma unroll
        for (int s = 0; s < 4; ++s) gacc[j][s] = (f32x4){0.f, 0.f, 0.f, 0.f};
    f32x4 xacc = (f32x4){0.f, 0.f, 0.f, 0.f};
    bf16x8 af[4];                     // XL row l15 — B for H-tile AND A for Phase F

    #pragma unroll
    for (int k0 = 0; k0 < 4; ++k0) {
        af[k0] = *(const bf16x8*)(XL + SWZ_OFF(l15, 32 * k0 + 8 * lh));
        bf16x8 bj[4];
        #pragma unroll
        for (int j = 0; j < 4; ++j) {
            const int c = 64 * cg + 16 * j + l15;
            bj[j] = md_row8(MD, c, 8 * k0 + 2 * lh);   // 2 conflict-free b64
        }
        #pragma unroll
        for (int s = 0; s < 4; ++s) {
            const int mt = 4 * rg + s;
            bf16x8 a = *(const bf16x8*)(AL + SWZ_OFF(16 * mt + l15, 32 * k0 + 8 * lh));
            #pragma unroll
            for (int j = 0; j < 4; ++j)
                gacc[j][s] = __builtin_amdgcn_mfma_f32_16x16x32_bf16(a, bj[j], gacc[j][s], 0, 0, 0);
        }
        // H-tile rows 16w..16w+15: C[d][b] = sum_e a[d][e] X[b][e]; B = af (X rows)
        {
            bf16x8 aH = *(const bf16x8*)(AL + SWZ_OFF(16 * w + l15, 32 * k0 + 8 * lh));
            xacc = __builtin_amdgcn_mfma_f32_16x16x32_bf16(aH, af[k0], xacc, 0, 0, 0);
        }
    }

    // xax partial: lane (b=l15, lh) holds H[16w+4lh+r][b]; dot with x[b][same d]
    {
        uint2 pk = *(const uint2*)(XL + SWZ_OFF(l15, 16 * w + 4 * lh));
        float v = bfu2f((unsigned short)(pk.x & 0xffffu)) * xacc[0];
        v = fmaf(bfu2f((unsigned short)(pk.x >> 16)),     xacc[1], v);
        v = fmaf(bfu2f((unsigned short)(pk.y & 0xffffu)), xacc[2], v);
        v = fmaf(bfu2f((unsigned short)(pk.y >> 16)),     xacc[3], v);
        v += __shfl_xor(v, 16);
        v += __shfl_xor(v, 32);
        if (lane < 16) SXAX[w][lane] = v;
    }

    // ---------- Phase D: partial t[c] over this wave's d-half (conflict-free b64) ----------
    {
        float tpart[4];
        #pragma unroll
        for (int j = 0; j < 4; ++j) {
            const int c = 64 * cg + 16 * j + l15;
            float v = 0.f;
            #pragma unroll
            for (int s = 0; s < 4; ++s) {
                const int mt = 4 * rg + s;
                uint2 mm = *(const uint2*)(MD + MD_OFF(c, 4 * mt + lh));
                v = fmaf(bfu2f((unsigned short)(mm.x & 0xffffu)), gacc[j][s][0], v);
                v = fmaf(bfu2f((unsigned short)(mm.x >> 16)),     gacc[j][s][1], v);
                v = fmaf(bfu2f((unsigned short)(mm.y & 0xffffu)), gacc[j][s][2], v);
                v = fmaf(bfu2f((unsigned short)(mm.y >> 16)),     gacc[j][s][3], v);
            }
            v += __shfl_xor(v, 16);   // reduce over lh (butterfly, all lanes get sum)
            v += __shfl_xor(v, 32);
            tpart[j] = v;
        }
        if (lane < 16)
            #pragma unroll
            for (int j = 0; j < 4; ++j) TP[rg][64 * cg + 16 * j + lane] = tpart[j];
    }
    __syncthreads();   // other waves' C/D means-reads (full d-range) before E writes

    // ---------- Phase E: overwrite MD with G' (this wave's (c, d-half) slots) ----------
    #pragma unroll
    for (int j = 0; j < 4; ++j) {
        const int c = 64 * cg + 16 * j + l15;
        #pragma unroll
        for (int s = 0; s < 4; ++s) {
            const int mt = 4 * rg + s;
            uint2 pk;
            pk.x = pk2(gacc[j][s][0], gacc[j][s][1]);
            pk.y = pk2(gacc[j][s][2], gacc[j][s][3]);
            *(uint2*)(MD + MD_OFF(c, 4 * mt + lh)) = pk;
        }
    }
    __syncthreads();

    // ---------- Phase F: S' = X*G' -- wave w: tiles 2w, 2w+1 of 16 (af reused) ----------
    bf16x8 bf2[2][4];
    #pragma unroll
    for (int j2 = 0; j2 < 2; ++j2) {
        const int rowc = 16 * (2 * w + j2) + l15;
        #pragma unroll
        for (int k0 = 0; k0 < 4; ++k0)
            bf2[j2][k0] = md_row8(MD, rowc, 8 * k0 + 2 * lh);
    }
    f32x4 macc[2];
    #pragma unroll
    for (int j2 = 0; j2 < 2; ++j2) macc[j2] = (f32x4){0.f, 0.f, 0.f, 0.f};
    #pragma unroll
    for (int k0 = 0; k0 < 4; ++k0)
        #pragma unroll
        for (int j2 = 0; j2 < 2; ++j2)
            macc[j2] = __builtin_amdgcn_mfma_f32_16x16x32_bf16(af[k0], bf2[j2][k0], macc[j2], 0, 0, 0);

    // epilogue: C layout col=l15 (=c within tile), row=4lh+reg (=b)
    {
        float mr[4];
        #pragma unroll
        for (int r = 0; r < 4; ++r) mr[r] = 1e30f;
        #pragma unroll
        for (int j2 = 0; j2 < 2; ++j2) {
            const int c = 16 * (2 * w + j2) + l15;
            const float tc = TP[0][c] + TP[1][c];
            #pragma unroll
            for (int r = 0; r < 4; ++r)
                mr[r] = fminf(mr[r], tc - 2.f * macc[j2][r]);   // -2 x^T (a m_c)
        }
        #pragma unroll
        for (int r = 0; r < 4; ++r) {
            #pragma unroll
            for (int m = 1; m < 16; m <<= 1)
                mr[r] = fminf(mr[r], __shfl_xor(mr[r], m));
        }
        if (l15 == 0)
            #pragma unroll
            for (int r = 0; r < 4; ++r) SMIN[w][4 * lh + r] = mr[r];
    }
    __syncthreads();

    if (tid < 16) {
        float mnv = 1e30f, xa = 0.f;
        #pragma unroll
        for (int w8 = 0; w8 < 8; ++w8) {
            mnv = fminf(mnv, SMIN[w8][tid]);
            xa += SXAX[w8][tid];
        }
        out[b0 + tid] = xa + mnv;   // xa = x^T a x
    }
}

extern "C" void kernel_launch(void* const* d_in, const int* in_sizes, int n_in,
                              void* d_out, int out_size, void* d_ws, size_t ws_size,
                              hipStream_t stream) {
    const float* X     = (const float*)d_in[0];
    const float* means = (const float*)d_in[1];
    const float* alpha = (const float*)d_in[2];
    float* out = (float*)d_out;
    fused_kernel<<<Bn / 16, 512, 0, stream>>>(X, means, alpha, out);
}